// Round 1
// 369.638 us; speedup vs baseline: 1.2494x; 1.2494x over previous
//
#include <hip/hip_runtime.h>
#include <stdint.h>

// Problem constants
#define N_S   16
#define C_IN  256
#define CMID  64
#define HH    96
#define WW    96
#define HW    9216     // 96*96
#define PL2   128      // PLANES/2

// smalls[] fp32 layout (element offsets)
#define CB_OFF   0     // conv_b[64]
#define KW_OFF   64    // conv_kernel_w[25]
#define KB_OFF   96    // conv_kernel_b[25]
#define K2W_OFF  128   // conv_kernel2_w[9]
#define K2B_OFF  144   // conv_kernel2_b[9]
#define FB_OFF   160   // fuse_b[128]
#define AB_OFF   288   // adap_b[64]
#define ATB_OFF  352   // atrous_b[64]
#define SC_OFF   416   // conv_k_w, conv_k_b, conv_k2_w, conv_k2_b

typedef __attribute__((ext_vector_type(8))) short short8;   // 8 bf16 = 4 VGPRs
typedef __attribute__((ext_vector_type(4))) float floatx4;  // MFMA acc

// ---------- bf16 helpers ----------
__device__ __forceinline__ float ldbf(const uint16_t* p) {
    return __uint_as_float(((uint32_t)(*p)) << 16);
}
__device__ __forceinline__ uint16_t f2bf(float f) {
    uint32_t u = __float_as_uint(f);
    u = (u + 0x7fffu + ((u >> 16) & 1u)) >> 16;   // RTNE
    return (uint16_t)u;
}
__device__ __forceinline__ float bfsum2(uint32_t u) {     // sum of packed bf16 pair
    return __uint_as_float(u << 16) + __uint_as_float(u & 0xffff0000u);
}

// ---------- P0: dtype probe + weight normalization (merged) ----------
__global__ __launch_bounds__(256) void k_prep(
    const uint16_t* __restrict__ xq,
    const void* conv_w, const void* conv_b, const void* ckw, const void* ckb,
    const void* ck2w, const void* ck2b, const void* kernw, const void* kernb,
    const void* kern2w, const void* kern2b, const void* fuse_w, const void* fuse_b,
    const void* adap_b, const void* atrous_b,
    int* __restrict__ flags,
    uint16_t* __restrict__ cw_bf, uint16_t* __restrict__ fw_bf,
    float* __restrict__ smalls) {
    __shared__ int cnt[2];
    int t = threadIdx.x;
    if (t < 2) cnt[t] = 0;
    __syncthreads();
    int cx = 0, cw = 0;
    const uint16_t* wq = (const uint16_t*)conv_w;
    for (int k = 0; k < 64; ++k) {
        uint16_t vx = xq[k * 256 + t];
        uint16_t vw = wq[k * 256 + t];
        if (((vx >> 7) & 0xFF) >= 0xC0) cx++;
        if (((vw >> 7) & 0xFF) >= 0xC0) cw++;
    }
    atomicAdd(&cnt[0], cx);
    atomicAdd(&cnt[1], cw);
    __syncthreads();
    if (t == 0) { flags[0] = cnt[0] > 64; flags[1] = cnt[1] > 64; }
    bool f32 = cnt[1] > 64;

    for (int i = t; i < CMID * C_IN; i += 256)
        cw_bf[i] = f32 ? f2bf(((const float*)conv_w)[i]) : ((const uint16_t*)conv_w)[i];
    for (int i = t; i < PL2 * CMID; i += 256)
        fw_bf[i] = f32 ? f2bf(((const float*)fuse_w)[i]) : ((const uint16_t*)fuse_w)[i];
    if (t < 64) {
        smalls[CB_OFF + t]  = f32 ? ((const float*)conv_b)[t]   : ldbf((const uint16_t*)conv_b + t);
        smalls[AB_OFF + t]  = f32 ? ((const float*)adap_b)[t]   : ldbf((const uint16_t*)adap_b + t);
        smalls[ATB_OFF + t] = f32 ? ((const float*)atrous_b)[t] : ldbf((const uint16_t*)atrous_b + t);
    }
    if (t < 128)
        smalls[FB_OFF + t] = f32 ? ((const float*)fuse_b)[t] : ldbf((const uint16_t*)fuse_b + t);
    if (t < 25) {
        smalls[KW_OFF + t] = f32 ? ((const float*)kernw)[t] : ldbf((const uint16_t*)kernw + t);
        smalls[KB_OFF + t] = f32 ? ((const float*)kernb)[t] : ldbf((const uint16_t*)kernb + t);
    }
    if (t < 9) {
        smalls[K2W_OFF + t] = f32 ? ((const float*)kern2w)[t] : ldbf((const uint16_t*)kern2w + t);
        smalls[K2B_OFF + t] = f32 ? ((const float*)kern2b)[t] : ldbf((const uint16_t*)kern2b + t);
    }
    if (t == 0) {
        smalls[SC_OFF + 0] = f32 ? ((const float*)ckw)[0]  : ldbf((const uint16_t*)ckw);
        smalls[SC_OFF + 1] = f32 ? ((const float*)ckb)[0]  : ldbf((const uint16_t*)ckb);
        smalls[SC_OFF + 2] = f32 ? ((const float*)ck2w)[0] : ldbf((const uint16_t*)ck2w);
        smalls[SC_OFF + 3] = f32 ? ((const float*)ck2b)[0] : ldbf((const uint16_t*)ck2b);
    }
}

// ---------- K1: f = relu(1x1 conv) via MFMA + fused per-channel partial sums ----------
// grid: 16 * 72 tiles of 128 px; block 256 (4 waves); A-frags from global (L2-resident)
__global__ __launch_bounds__(256, 4) void k_conv1x1(
    const void* __restrict__ xv, const int* __restrict__ flags,
    const uint16_t* __restrict__ cw_bf, const float* __restrict__ smalls,
    uint16_t* __restrict__ fout, float* __restrict__ partials) {
    __shared__ uint16_t x_lds[128 * 72];      // [px][c-chunk] pad 72 -> 18432 B
    int t = threadIdx.x;
    int b = blockIdx.x;
    int n = b / 72, blk = b % 72;
    int pxb = blk * 128;
    bool xf32 = flags[0] != 0;

    int lane = t & 63, wid = t >> 6;
    int l16 = lane & 15, quad = lane >> 4;
    int nb = wid * 32;
    uint32_t* xl32 = (uint32_t*)x_lds;        // [px] stride 36 uints

    floatx4 acc[4][2];
#pragma unroll
    for (int i = 0; i < 4; ++i)
#pragma unroll
        for (int j = 0; j < 2; ++j) acc[i][j] = (floatx4){0.f, 0.f, 0.f, 0.f};

    float* pbase = partials + (size_t)(n * 72 + blk) * 256;

    for (int cc = 0; cc < 4; ++cc) {          // K chunks of 64 c
        __syncthreads();
        // stage+transpose 64c x 128px: pairs (c,c+1) packed per px; also partial sums
#pragma unroll
        for (int k = 0; k < 2; ++k) {
            int task = k * 256 + t;
            int pxg = task & 15, cp = task >> 4;      // cp 0..31
            int c = cc * 64 + cp * 2;
            int px0 = pxb + pxg * 8;
            uint16_t r0[8], r1[8];
            float s0, s1;
            if (xf32) {
                const float* xb = (const float*)xv + ((size_t)n * C_IN + c) * HW + px0;
                float4 a0 = *(const float4*)xb, a1 = *(const float4*)(xb + 4);
                float4 b0 = *(const float4*)(xb + HW), b1 = *(const float4*)(xb + HW + 4);
                s0 = (a0.x + a0.y + a0.z + a0.w) + (a1.x + a1.y + a1.z + a1.w);
                s1 = (b0.x + b0.y + b0.z + b0.w) + (b1.x + b1.y + b1.z + b1.w);
                r0[0]=f2bf(a0.x); r0[1]=f2bf(a0.y); r0[2]=f2bf(a0.z); r0[3]=f2bf(a0.w);
                r0[4]=f2bf(a1.x); r0[5]=f2bf(a1.y); r0[6]=f2bf(a1.z); r0[7]=f2bf(a1.w);
                r1[0]=f2bf(b0.x); r1[1]=f2bf(b0.y); r1[2]=f2bf(b0.z); r1[3]=f2bf(b0.w);
                r1[4]=f2bf(b1.x); r1[5]=f2bf(b1.y); r1[6]=f2bf(b1.z); r1[7]=f2bf(b1.w);
            } else {
                const uint16_t* xb = (const uint16_t*)xv + ((size_t)n * C_IN + c) * HW + px0;
                uint4 v0 = *(const uint4*)xb;
                uint4 v1 = *(const uint4*)(xb + HW);
                s0 = (bfsum2(v0.x) + bfsum2(v0.y)) + (bfsum2(v0.z) + bfsum2(v0.w));
                s1 = (bfsum2(v1.x) + bfsum2(v1.y)) + (bfsum2(v1.z) + bfsum2(v1.w));
                r0[0]=(uint16_t)v0.x; r0[1]=(uint16_t)(v0.x>>16);
                r0[2]=(uint16_t)v0.y; r0[3]=(uint16_t)(v0.y>>16);
                r0[4]=(uint16_t)v0.z; r0[5]=(uint16_t)(v0.z>>16);
                r0[6]=(uint16_t)v0.w; r0[7]=(uint16_t)(v0.w>>16);
                r1[0]=(uint16_t)v1.x; r1[1]=(uint16_t)(v1.x>>16);
                r1[2]=(uint16_t)v1.y; r1[3]=(uint16_t)(v1.y>>16);
                r1[4]=(uint16_t)v1.z; r1[5]=(uint16_t)(v1.z>>16);
                r1[6]=(uint16_t)v1.w; r1[7]=(uint16_t)(v1.w>>16);
            }
#pragma unroll
            for (int j = 0; j < 8; ++j)
                xl32[(pxg * 8 + j) * 36 + cp] = (uint32_t)r0[j] | ((uint32_t)r1[j] << 16);
            // reduce the 128-px partial sums across the 16 lanes sharing this c-pair
#pragma unroll
            for (int off = 8; off > 0; off >>= 1) {
                s0 += __shfl_xor(s0, off, 16);
                s1 += __shfl_xor(s1, off, 16);
            }
            if ((t & 15) == 0) *(float2*)(pbase + c) = make_float2(s0, s1);
        }
        __syncthreads();
        // MFMA: A[m=o][k] from global cw_bf (L2), B[k][n=px] from LDS
#pragma unroll
        for (int ks = 0; ks < 2; ++ks) {
            int kw = cc * 64 + ks * 32 + quad * 8;
            int kx = ks * 32 + quad * 8;
            const uint16_t* wp = cw_bf + kw;
            short8 a0 = *(const short8*)(wp + (l16)      * 256);
            short8 a1 = *(const short8*)(wp + (16 + l16) * 256);
            short8 a2 = *(const short8*)(wp + (32 + l16) * 256);
            short8 a3 = *(const short8*)(wp + (48 + l16) * 256);
#pragma unroll
            for (int nt = 0; nt < 2; ++nt) {
                short8 bv = *(const short8*)(x_lds + (nb + nt * 16 + l16) * 72 + kx);
                acc[0][nt] = __builtin_amdgcn_mfma_f32_16x16x32_bf16(a0, bv, acc[0][nt], 0, 0, 0);
                acc[1][nt] = __builtin_amdgcn_mfma_f32_16x16x32_bf16(a1, bv, acc[1][nt], 0, 0, 0);
                acc[2][nt] = __builtin_amdgcn_mfma_f32_16x16x32_bf16(a2, bv, acc[2][nt], 0, 0, 0);
                acc[3][nt] = __builtin_amdgcn_mfma_f32_16x16x32_bf16(a3, bv, acc[3][nt], 0, 0, 0);
            }
        }
    }

    // epilogue: D[col=px=l16][row=o=quad*4+reg]; bias+relu+bf16 -> x_lds [px][o]
    __syncthreads();
#pragma unroll
    for (int mt = 0; mt < 4; ++mt) {
        int o = mt * 16 + quad * 4;
        float b0 = smalls[CB_OFF + o],     b1 = smalls[CB_OFF + o + 1];
        float b2 = smalls[CB_OFF + o + 2], b3 = smalls[CB_OFF + o + 3];
#pragma unroll
        for (int nt = 0; nt < 2; ++nt) {
            int pxl = nb + nt * 16 + l16;
            float v0 = fmaxf(acc[mt][nt][0] + b0, 0.f);
            float v1 = fmaxf(acc[mt][nt][1] + b1, 0.f);
            float v2 = fmaxf(acc[mt][nt][2] + b2, 0.f);
            float v3 = fmaxf(acc[mt][nt][3] + b3, 0.f);
            uint32_t lo = (uint32_t)f2bf(v0) | ((uint32_t)f2bf(v1) << 16);
            uint32_t hi = (uint32_t)f2bf(v2) | ((uint32_t)f2bf(v3) << 16);
            *(uint2*)(x_lds + pxl * 72 + o) = make_uint2(lo, hi);
        }
    }
    __syncthreads();
    // coalesced copy-out: f[n][pxb+pxl][o]
#pragma unroll
    for (int k = 0; k < 4; ++k) {
        int task = k * 256 + t;
        int o8 = (task & 7) * 8, pxl = task >> 3;
        *(uint4*)(fout + ((size_t)n * HW + pxb + pxl) * 64 + o8) =
            *(const uint4*)(x_lds + pxl * 72 + o8);
    }
}

// ---------- K2: reduce partials -> g -> dynamic depthwise weights ----------
__global__ __launch_bounds__(256) void k_weights2(
    const float* __restrict__ partials, const uint16_t* __restrict__ cw_bf,
    const float* __restrict__ smalls,
    float* __restrict__ w_dyn, float* __restrict__ w_atr) {
    __shared__ float s_sums[256];
    __shared__ float s_dot[256];
    int n = blockIdx.x, t = threadIdx.x;
    const float* pp = partials + (size_t)n * 72 * 256 + t;
    float s = 0.f;
#pragma unroll 8
    for (int k = 0; k < 72; ++k) s += pp[k * 256];
    s_sums[t] = s * (1.0f / (float)HW);
    __syncthreads();
    // split the 256-c dot across 4 thread segments
    int cm = t & 63, seg = t >> 6;
    const uint16_t* wr = cw_bf + cm * 256 + seg * 64;
    const float* sr = s_sums + seg * 64;
    float acc = 0.f;
#pragma unroll 8
    for (int c = 0; c < 64; ++c) acc = fmaf(ldbf(wr + c), sr[c], acc);
    s_dot[t] = acc;
    __syncthreads();
    if (t < 64) {
        float a = s_dot[t] + s_dot[t + 64] + s_dot[t + 128] + s_dot[t + 192]
                + smalls[CB_OFF + t];
        float gv = fmaxf(a, 0.f);
        float ckw = smalls[SC_OFF + 0], ckb = smalls[SC_OFF + 1];
        float ck2w = smalls[SC_OFF + 2], ck2b = smalls[SC_OFF + 3];
        float* o1 = w_dyn + (size_t)(n * CMID + t) * 25;
#pragma unroll
        for (int k = 0; k < 25; ++k)
            o1[k] = fmaf(ckw, fmaf(gv, smalls[KW_OFF + k], smalls[KB_OFF + k]), ckb);
        float* o2 = w_atr + (size_t)(n * CMID + t) * 9;
#pragma unroll
        for (int k = 0; k < 9; ++k)
            o2[k] = fmaf(ck2w, fmaf(gv, smalls[K2W_OFF + k], smalls[K2B_OFF + k]), ck2b);
    }
}

// ---------- K3: dynamic depthwise (5x5 + atrous 3x3) + MFMA fuse GEMM ----------
// Tile 4x16 px (64B store runs). f_lds XOR-swizzled stride 64. fw from global.
// LDS = 20480 + 2*9216 = 38912 B -> 4 blocks/CU (vs 2 before).
__global__ __launch_bounds__(256, 4) void k_dwfuse(
    const uint16_t* __restrict__ f,
    const float* __restrict__ w_dyn, const float* __restrict__ w_atr,
    const uint16_t* __restrict__ fw_bf, const float* __restrict__ smalls,
    float* __restrict__ out) {
    __shared__ uint16_t f_lds[160 * 64];      // halo 8x20 rows, swizzled c: 20480 B
    __shared__ uint16_t d5_lds[64 * 72];      // [px 4x16][c] pad 72: 9216 B
    __shared__ uint16_t dA_lds[64 * 72];      // 9216 B

    int t = threadIdx.x;
    int b = blockIdx.x;
    int n = b / 144, tile = b % 144;
    int y0 = (tile / 6) * 4, x0 = (tile % 6) * 16;

    // prefetch per-channel dynamic weights early (hide L2 latency under staging)
    int c = t >> 2, q = t & 3;
    int qx = q << 2;
    float w5[25], w9[9];
    {
        const float* wp = w_dyn + (size_t)(n * CMID + c) * 25;
#pragma unroll
        for (int k = 0; k < 25; ++k) w5[k] = wp[k];
        const float* wa = w_atr + (size_t)(n * CMID + c) * 9;
#pragma unroll
        for (int k = 0; k < 9; ++k) w9[k] = wa[k];
    }

    // stage f halo 8 rows x 20 cols x 64c (zero-padded); 1280 uint4 tasks
    const uint16_t* fbase = f + (size_t)n * HW * 64;
#pragma unroll
    for (int k = 0; k < 5; ++k) {
        int task = k * 256 + t;
        int row = task >> 3, c8 = (task & 7) * 8;
        int hy = row / 20, hx = row - hy * 20;
        int y = y0 - 2 + hy, xg = x0 - 2 + hx;
        uint4 v = make_uint4(0u, 0u, 0u, 0u);
        if (y >= 0 && y < HH && xg >= 0 && xg < WW)
            v = *(const uint4*)(fbase + ((size_t)y * WW + xg) * 64 + c8);
        *(uint4*)(f_lds + row * 64 + (c8 ^ ((row & 7) << 3))) = v;   // XOR swizzle
    }
    __syncthreads();

    // ---- depthwise: one channel x 4x4 patch per thread (rows 0..3, cols qx..qx+3) ----
    {
        float p[8][8];
#pragma unroll
        for (int r = 0; r < 8; ++r)
#pragma unroll
            for (int cl = 0; cl < 8; ++cl) {
                int row = r * 20 + qx + cl;
                p[r][cl] = ldbf(f_lds + row * 64 + (c ^ ((row & 7) << 3)));
            }

        float b5v = smalls[AB_OFF + c], bAv = smalls[ATB_OFF + c];
        float a5[4][4], aA[4][4];
#pragma unroll
        for (int i = 0; i < 4; ++i)
#pragma unroll
            for (int j = 0; j < 4; ++j) { a5[i][j] = b5v; aA[i][j] = bAv; }

#pragma unroll
        for (int i = 0; i < 5; ++i)
#pragma unroll
            for (int j = 0; j < 5; ++j) {
                float wv = w5[i * 5 + j];
#pragma unroll
                for (int oy = 0; oy < 4; ++oy)
#pragma unroll
                    for (int ox = 0; ox < 4; ++ox)
                        a5[oy][ox] = fmaf(wv, p[oy + i][ox + j], a5[oy][ox]);
            }
#pragma unroll
        for (int i = 0; i < 3; ++i)
#pragma unroll
            for (int j = 0; j < 3; ++j) {
                float wv = w9[i * 3 + j];
#pragma unroll
                for (int oy = 0; oy < 4; ++oy)
#pragma unroll
                    for (int ox = 0; ox < 4; ++ox)
                        aA[oy][ox] = fmaf(wv, p[oy + 2 * i][ox + 2 * j], aA[oy][ox]);
            }

#pragma unroll
        for (int oy = 0; oy < 4; ++oy)
#pragma unroll
            for (int ox = 0; ox < 4; ++ox) {
                int pxo = oy * 16 + qx + ox;          // row-major 4x16
                d5_lds[pxo * 72 + c] = f2bf(a5[oy][ox]);
                dA_lds[pxo * 72 + c] = f2bf(aA[oy][ox]);
            }
    }
    __syncthreads();

    // ---- fuse GEMM, operands SWAPPED: A = d[px][c] (LDS), B = fw^T (global) ----
    // D: row = px (quad*4+reg -> 4 consecutive x), col = o (l16) -> float4 stores
    {
        int lane = t & 63, wid = t >> 6;
        int l16 = lane & 15, quad = lane >> 4;
        const uint16_t* dl = (wid >= 2) ? dA_lds : d5_lds;
        int oh = (wid & 1) * 64;
        int obr = (wid >= 2) ? 128 : 0;

        floatx4 acc[4][4];                    // [mt=px group][nt=o group]
#pragma unroll
        for (int i = 0; i < 4; ++i)
#pragma unroll
            for (int j = 0; j < 4; ++j) acc[i][j] = (floatx4){0.f, 0.f, 0.f, 0.f};

#pragma unroll
        for (int ks = 0; ks < 2; ++ks) {
            int kk = ks * 32 + quad * 8;
            short8 a0 = *(const short8*)(dl + (l16)      * 72 + kk);
            short8 a1 = *(const short8*)(dl + (16 + l16) * 72 + kk);
            short8 a2 = *(const short8*)(dl + (32 + l16) * 72 + kk);
            short8 a3 = *(const short8*)(dl + (48 + l16) * 72 + kk);
#pragma unroll
            for (int nt = 0; nt < 4; ++nt) {
                short8 bv = *(const short8*)(fw_bf + (size_t)(oh + nt * 16 + l16) * 64 + kk);
                acc[0][nt] = __builtin_amdgcn_mfma_f32_16x16x32_bf16(a0, bv, acc[0][nt], 0, 0, 0);
                acc[1][nt] = __builtin_amdgcn_mfma_f32_16x16x32_bf16(a1, bv, acc[1][nt], 0, 0, 0);
                acc[2][nt] = __builtin_amdgcn_mfma_f32_16x16x32_bf16(a2, bv, acc[2][nt], 0, 0, 0);
                acc[3][nt] = __builtin_amdgcn_mfma_f32_16x16x32_bf16(a3, bv, acc[3][nt], 0, 0, 0);
            }
        }
        // store: px = mt*16 + quad*4 + reg -> y = y0+mt, x = x0 + quad*4 + reg
#pragma unroll
        for (int nt = 0; nt < 4; ++nt) {
            int o = oh + nt * 16 + l16;
            float bias = smalls[FB_OFF + o];
            float* obp = out + ((size_t)(n * 256 + obr + o)) * HW + x0 + quad * 4;
#pragma unroll
            for (int mt = 0; mt < 4; ++mt) {
                float4 v;
                v.x = acc[mt][nt][0] + bias;
                v.y = acc[mt][nt][1] + bias;
                v.z = acc[mt][nt][2] + bias;
                v.w = acc[mt][nt][3] + bias;
                *(float4*)(obp + (size_t)(y0 + mt) * WW) = v;
            }
        }
    }
}

extern "C" void kernel_launch(void* const* d_in, const int* in_sizes, int n_in,
                              void* d_out, int out_size, void* d_ws, size_t ws_size,
                              hipStream_t stream) {
    float* out = (float*)d_out;                              // fp32 output

    char* ws = (char*)d_ws;
    int*      flags = (int*)ws;                              // 256 B
    uint16_t* cw_bf = (uint16_t*)(ws + 256);                 // 32768 B [o][c]
    uint16_t* fw_bf = (uint16_t*)(ws + 33024);               // 16384 B [o][c]
    float*    smalls = (float*)(ws + 49408);                 // 2048 B
    float*    partials = (float*)(ws + 65536);               // 1179648 B [n][72][256]
    float*    w_dyn = (float*)(ws + 1245184);                // 102400 B
    float*    w_atr = (float*)(ws + 1347584);                // 36864 B
    uint16_t* f     = (uint16_t*)(ws + 1384448);             // 18.9 MB [n][px][c] bf16

    k_prep<<<dim3(1), dim3(256), 0, stream>>>(
        (const uint16_t*)d_in[0],
        d_in[1], d_in[2], d_in[3], d_in[4], d_in[5], d_in[6], d_in[7], d_in[8],
        d_in[9], d_in[10], d_in[11], d_in[12], d_in[13], d_in[14],
        flags, cw_bf, fw_bf, smalls);
    k_conv1x1<<<dim3(N_S * 72), dim3(256), 0, stream>>>(
        d_in[0], flags, cw_bf, smalls, f, partials);
    k_weights2<<<dim3(N_S), dim3(256), 0, stream>>>(
        partials, cw_bf, smalls, w_dyn, w_atr);
    k_dwfuse<<<dim3(N_S * 144), dim3(256), 0, stream>>>(
        f, w_dyn, w_atr, fw_bf, smalls, out);
}